// Round 7
// baseline (432.070 us; speedup 1.0000x reference)
//
#include <hip/hip_runtime.h>

typedef unsigned short u16;
typedef unsigned int u32;
typedef __attribute__((ext_vector_type(8))) __bf16 bf16x8;
typedef __attribute__((ext_vector_type(4))) float f32x4;
typedef __attribute__((ext_vector_type(16))) float f32x16;

#define SEQ   2048
#define NH    71
#define HD    64
#define HID   4544   // 71*64
#define NQKV  4672   // 73*64
#define KP    4608   // K padded to 72*64
#define KSL   1536   // split-K slice (KP/3); 48 K-tiles of 32

__device__ __forceinline__ u16 f2bf(float f) {
    __bf16 b = (__bf16)f;
    return __builtin_bit_cast(u16, b);
}
__device__ __forceinline__ float bf2f(u16 u) {
    __bf16 b = __builtin_bit_cast(__bf16, u);
    return (float)b;
}

__device__ __forceinline__ void gload_lds16(const u16* g, u16* l) {
    __builtin_amdgcn_global_load_lds(
        (const __attribute__((address_space(1))) u32*)g,
        (__attribute__((address_space(3))) u32*)l, 16, 0, 0);
}

// ---------------- f32 -> bf16, K-padded rows (zero pad) ----------------
__global__ __launch_bounds__(256) void k_convert(const float* __restrict__ in,
                                                 u16* __restrict__ out) {
    const int row = blockIdx.x;
    const float* src = in + (size_t)row * HID;
    u16* dst = out + (size_t)row * KP;
    for (int c = threadIdx.x; c < KP / 8; c += 256) {
        u16 o[8];
        if (c < HID / 8) {
            float4 v0 = *(const float4*)(src + c * 8);
            float4 v1 = *(const float4*)(src + c * 8 + 4);
            o[0] = f2bf(v0.x); o[1] = f2bf(v0.y); o[2] = f2bf(v0.z); o[3] = f2bf(v0.w);
            o[4] = f2bf(v1.x); o[5] = f2bf(v1.y); o[6] = f2bf(v1.z); o[7] = f2bf(v1.w);
        } else {
#pragma unroll
            for (int j = 0; j < 8; ++j) o[j] = 0;
        }
        *(uint4*)(dst + c * 8) = *(uint4*)o;
    }
}

// ----- transpose+convert: in[R][C] f32 -> out[Cp][Rp] bf16, zero-padded -----
__global__ __launch_bounds__(256) void k_transpose(const float* __restrict__ in,
                                                   u16* __restrict__ out,
                                                   int R, int C, int Rp) {
    __shared__ float tile[32][33];
    int c0 = blockIdx.x * 32, r0 = blockIdx.y * 32;
    int tx = threadIdx.x & 31, ty = threadIdx.x >> 5;
#pragma unroll
    for (int i = 0; i < 32; i += 8) {
        int r = r0 + ty + i, c = c0 + tx;
        tile[ty + i][tx] = (r < R && c < C) ? in[(size_t)r * C + c] : 0.f;
    }
    __syncthreads();
#pragma unroll
    for (int i = 0; i < 32; i += 8)
        out[(size_t)(c0 + ty + i) * Rp + r0 + tx] = f2bf(tile[tx][ty + i]);
}

// ---- split-K GEMM, 256x256 tile, BK=32, 4 LDS buffers, 3-deep prefetch ----
// 32x32x16 MFMA core (m119: 2495 TF pipe vs 2176 for 16x16 -> ~15% fewer
// MFMA-pipe cycles, half the MFMA instructions). LDS rows (128B) pack A-row
// chunks (slots c^(r&7), lower half) and B-row chunks (upper half XOR 4);
// fragment reads land 8 accesses/bank -> conflict-free (verified: 0 conflicts).
// Per K-tile: 2 phases {ds_read frags; stage 2 gloads; s_barrier; setprio(1);
// 8 MFMA; setprio(0); s_barrier}; counted vmcnt(8) once per tile.
// A-frag layout: row=lane&31, k=8*(lane>>5)+j. C: col=lane&31,
// row=(reg&3)+8*(reg>>2)+4*(lane>>5)  [m74/m101-verified].
template <bool BF16OUT>
__global__ __launch_bounds__(512) void k_gemm_sk(const u16* __restrict__ A,
                                                 const u16* __restrict__ BT,
                                                 char* __restrict__ C0,
                                                 char* __restrict__ C1,
                                                 char* __restrict__ C2,
                                                 int N, int ntN) {
    __shared__ u16 ls[4][256 * 64];            // 4 bufs x 32KB, packed A||B rows
    const int tid = threadIdx.x;
    const int lane = tid & 63;
    const int wid = tid >> 6;
    const int wr = wid >> 2, wc = wid & 3;     // 2 x 4 wave grid (128 x 64 out)
    const int l31 = lane & 31, hi = lane >> 5;

    const int p = blockIdx.x;
    const int m0 = (p & 7) * 256;              // XCD-chunk: XCD owns one m-strip
    const int rr_ = p >> 3;
    const int ks = rr_ / ntN;
    const int n0 = (rr_ % ntN) * 256;
    const int k0 = ks * KSL;

    // staging precompute: 4 gload insts/tile; inst i covers buffer rows
    // i*64 + wid*8 + (lane>>3); lane's slot = lane&7; source pre-swizzled.
    const int sg = lane >> 3;
    const int slot = lane & 7;
    const u16* sb[4];
    int dstoff[4];
#pragma unroll
    for (int i = 0; i < 4; ++i) {
        int r = i * 64 + wid * 8 + sg;
        int sc = slot ^ (r & 7);
        sb[i] = (sc < 4) ? (A  + (size_t)(m0 + r) * KP + k0 + sc * 8)
                         : (BT + (size_t)(n0 + r) * KP + k0 + (sc ^ 4) * 8);
        dstoff[i] = r * 64 + slot * 8;
    }

    f32x16 acc[8];   // [mi*2+ni]
#pragma unroll
    for (int i = 0; i < 8; ++i)
#pragma unroll
        for (int j = 0; j < 16; ++j) acc[i][j] = 0.f;

#define STG(d, kt, i) gload_lds16(sb[i] + (size_t)(kt) * 32, &ls[d][dstoff[i]])

    const int NT = KSL / 32;  // 48
    STG(0, 0, 0); STG(0, 0, 1); STG(0, 0, 2); STG(0, 0, 3);
    STG(1, 1, 0); STG(1, 1, 1); STG(1, 1, 2); STG(1, 1, 3);
    STG(2, 2, 0); STG(2, 2, 1); STG(2, 2, 2); STG(2, 2, 3);
    asm volatile("s_waitcnt vmcnt(8)" ::: "memory");
    __builtin_amdgcn_s_barrier();

    for (int kt = 0; kt < NT; ++kt) {
        const u16* L = ls[kt & 3];
        const int db = (kt + 3) & 3;
        const bool st = (kt + 3 < NT);
        bf16x8 bfr[2], af[4];
        // ---- phase 1 (kslice 0, chunk idx hi): ds_read 6 frags; stage 2; 8 MFMA
#pragma unroll
        for (int ni = 0; ni < 2; ++ni) {
            int rb = wc * 64 + ni * 32 + l31;
            bfr[ni] = *(const bf16x8*)(L + rb * 64 + (((hi ^ 4) ^ (rb & 7)) << 3));
        }
#pragma unroll
        for (int mi = 0; mi < 4; ++mi) {
            int ra = wr * 128 + mi * 32 + l31;
            af[mi] = *(const bf16x8*)(L + ra * 64 + ((hi ^ (ra & 7)) << 3));
        }
        if (st) { STG(db, kt + 3, 0); STG(db, kt + 3, 1); }
        __builtin_amdgcn_s_barrier();
        __builtin_amdgcn_s_setprio(1);
#pragma unroll
        for (int mi = 0; mi < 4; ++mi)
#pragma unroll
            for (int ni = 0; ni < 2; ++ni)
                acc[mi * 2 + ni] = __builtin_amdgcn_mfma_f32_32x32x16_bf16(
                    af[mi], bfr[ni], acc[mi * 2 + ni], 0, 0, 0);
        __builtin_amdgcn_s_setprio(0);
        __builtin_amdgcn_s_barrier();
        // ---- phase 2 (kslice 1, chunk idx 2+hi): ds_read 6; stage 2; 8 MFMA
#pragma unroll
        for (int ni = 0; ni < 2; ++ni) {
            int rb = wc * 64 + ni * 32 + l31;
            bfr[ni] = *(const bf16x8*)(L + rb * 64 + ((((2 + hi) ^ 4) ^ (rb & 7)) << 3));
        }
#pragma unroll
        for (int mi = 0; mi < 4; ++mi) {
            int ra = wr * 128 + mi * 32 + l31;
            af[mi] = *(const bf16x8*)(L + ra * 64 + (((2 + hi) ^ (ra & 7)) << 3));
        }
        if (st) { STG(db, kt + 3, 2); STG(db, kt + 3, 3); }
        __builtin_amdgcn_s_barrier();
        __builtin_amdgcn_s_setprio(1);
#pragma unroll
        for (int mi = 0; mi < 4; ++mi)
#pragma unroll
            for (int ni = 0; ni < 2; ++ni)
                acc[mi * 2 + ni] = __builtin_amdgcn_mfma_f32_32x32x16_bf16(
                    af[mi], bfr[ni], acc[mi * 2 + ni], 0, 0, 0);
        __builtin_amdgcn_s_setprio(0);
        // counted wait: guarantee tile kt+1 landed before next tile's ds_reads
        if (kt < NT - 3)       asm volatile("s_waitcnt vmcnt(8)" ::: "memory");
        else if (kt == NT - 3) asm volatile("s_waitcnt vmcnt(4)" ::: "memory");
        else if (kt == NT - 2) asm volatile("s_waitcnt vmcnt(0)" ::: "memory");
        __builtin_amdgcn_s_barrier();
    }
#undef STG

    char* Cks = (ks == 0) ? C0 : (ks == 1) ? C1 : C2;
#pragma unroll
    for (int mi = 0; mi < 4; ++mi)
#pragma unroll
        for (int ni = 0; ni < 2; ++ni) {
            int col = n0 + wc * 64 + ni * 32 + l31;
            if (col < N) {
#pragma unroll
                for (int rg = 0; rg < 4; ++rg)
#pragma unroll
                    for (int j = 0; j < 4; ++j) {
                        int row = m0 + wr * 128 + mi * 32 + rg * 8 + hi * 4 + j;
                        float v = acc[mi * 2 + ni][rg * 4 + j];
                        if (BF16OUT) ((u16*)Cks)[(size_t)row * N + col] = f2bf(v);
                        else         ((float*)Cks)[(size_t)row * N + col] = v;
                    }
            }
        }
}

// -------- dense split-K reduction: out += P1 + P2 (f32, float4) --------
__global__ __launch_bounds__(256) void k_reduce(float* __restrict__ out,
                                                const float* __restrict__ P1,
                                                const float* __restrict__ P2, int n4) {
    for (int i = blockIdx.x * 256 + threadIdx.x; i < n4; i += gridDim.x * 256) {
        float4 a = ((const float4*)out)[i];
        float4 b = ((const float4*)P1)[i];
        float4 c = ((const float4*)P2)[i];
        a.x += b.x + c.x; a.y += b.y + c.y; a.z += b.z + c.z; a.w += b.w + c.w;
        ((float4*)out)[i] = a;
    }
}

// ---------------- RoPE + split-K sum + split/transposed emit ----------------
__global__ __launch_bounds__(256) void k_rope(const u16* __restrict__ P0,
                                              const u16* __restrict__ P1,
                                              const u16* __restrict__ P2,
                                              const float* __restrict__ cosb,
                                              const float* __restrict__ sinb,
                                              u16* __restrict__ qb, u16* __restrict__ kb,
                                              u16* __restrict__ vT) {
    int s = blockIdx.x;
    __shared__ float row[NQKV];
    __shared__ float cs[64], sn[64];
    if (threadIdx.x < 64) {
        cs[threadIdx.x] = cosb[s * 64 + threadIdx.x];
        sn[threadIdx.x] = sinb[s * 64 + threadIdx.x];
    }
    const u16* r0 = P0 + (size_t)s * NQKV;
    const u16* r1 = P1 + (size_t)s * NQKV;
    const u16* r2 = P2 + (size_t)s * NQKV;
    for (int e = threadIdx.x; e < NQKV; e += 256)
        row[e] = bf2f(r0[e]) + bf2f(r1[e]) + bf2f(r2[e]);
    __syncthreads();
    const float qscale = 0.125f * 1.44269504f;
    for (int e = threadIdx.x; e < NQKV; e += 256) {
        int h = e >> 6, d = e & 63;
        float x = row[e];
        if (h < 72) {
            float other = row[h * 64 + ((d < 32) ? d + 32 : d - 32)];
            float rot = (d < 32) ? -other : other;
            float rr = x * cs[d] + rot * sn[d];
            if (h < NH) qb[((size_t)h * SEQ + s) * 64 + d] = f2bf(rr * qscale);
            else        kb[(size_t)s * 64 + d] = f2bf(rr);
        } else {
            vT[(size_t)d * SEQ + s] = f2bf(x);
        }
    }
}

// ---------------- Flash attention (round 4/5/6 structure + T5 setprio) ----------------
__global__ __launch_bounds__(512) void k_attn(const u16* __restrict__ qb,
                                              const u16* __restrict__ kb,
                                              const u16* __restrict__ vT,
                                              u16* __restrict__ ctx) {
    const int tid = threadIdx.x;
    const int lane = tid & 63;
    const int wid = tid >> 6;
    const int l15 = lane & 15, lg = lane >> 4;

    const int bid = blockIdx.x;
    const int qt = 63 - bid / 9;
    const int hg = bid % 9;
    int h = hg * 8 + wid;
    const bool hval = (h < NH);
    if (!hval) h = NH - 1;
    const int q0 = qt * 32;
    const int nt = (qt >> 2) + 1;

    __shared__ u16 lsK[2][128 * 64];
    __shared__ u16 lsV[2][64 * 128];
    __shared__ u16 lsP[8][32 * 128];
    u16* myP = lsP[wid];

    const int kr = tid >> 3, kc = tid & 7;
    const int vd = tid >> 4, vc = tid & 15;

    bf16x8 qf[2][2];
#pragma unroll
    for (int mi = 0; mi < 2; ++mi)
#pragma unroll
        for (int ks = 0; ks < 2; ++ks)
            qf[mi][ks] = *(const bf16x8*)(qb + ((size_t)h * SEQ + q0 + mi * 16 + l15) * 64
                                          + ks * 32 + lg * 8);

    f32x4 oacc[2][4];
#pragma unroll
    for (int i = 0; i < 2; ++i)
#pragma unroll
        for (int j = 0; j < 4; ++j) oacc[i][j] = (f32x4){0.f, 0.f, 0.f, 0.f};
    float mrun[2] = {-3e38f, -3e38f};
    float lrun[2] = {0.f, 0.f};

    uint4 kg0, kg1, vg0, vg1;
    kg0 = *(const uint4*)(kb + (size_t)kr * 64 + kc * 8);
    kg1 = *(const uint4*)(kb + (size_t)(kr + 64) * 64 + kc * 8);
    vg0 = *(const uint4*)(vT + (size_t)vd * SEQ + vc * 8);
    vg1 = *(const uint4*)(vT + (size_t)(vd + 32) * SEQ + vc * 8);
    {
        const int kswz = (kr & 7) << 4;
        *(uint4*)((char*)lsK[0] + kr * 128 + ((kc * 16) ^ kswz)) = kg0;
        *(uint4*)((char*)lsK[0] + (kr + 64) * 128 + ((kc * 16) ^ kswz)) = kg1;
        *(uint4*)((char*)lsV[0] + vd * 256 + ((vc * 16) ^ ((vd & 15) << 4))) = vg0;
        *(uint4*)((char*)lsV[0] + (vd + 32) * 256 + ((vc * 16) ^ (((vd + 32) & 15) << 4))) = vg1;
    }

    for (int t = 0; t < nt; ++t) {
        const int t0 = t << 7;
        const int cb = t & 1;
        if (t + 1 < nt) {
            const int t1 = t0 + 128;
            kg0 = *(const uint4*)(kb + (size_t)(t1 + kr) * 64 + kc * 8);
            kg1 = *(const uint4*)(kb + (size_t)(t1 + kr + 64) * 64 + kc * 8);
            vg0 = *(const uint4*)(vT + (size_t)vd * SEQ + t1 + vc * 8);
            vg1 = *(const uint4*)(vT + (size_t)(vd + 32) * SEQ + t1 + vc * 8);
        }
        __syncthreads();

        f32x4 sacc[2][8];
#pragma unroll
        for (int i = 0; i < 2; ++i)
#pragma unroll
            for (int j = 0; j < 8; ++j) sacc[i][j] = (f32x4){0.f, 0.f, 0.f, 0.f};
        __builtin_amdgcn_s_setprio(1);
#pragma unroll
        for (int ni = 0; ni < 8; ++ni) {
            const int rr = ni * 16 + l15;
            const int swz = (rr & 7) << 4;
            bf16x8 kf0 = *(const bf16x8*)((const char*)lsK[cb] + rr * 128 + ((lg * 16) ^ swz));
            bf16x8 kf1 = *(const bf16x8*)((const char*)lsK[cb] + rr * 128 + ((64 + lg * 16) ^ swz));
            sacc[0][ni] = __builtin_amdgcn_mfma_f32_16x16x32_bf16(kf0, qf[0][0], sacc[0][ni], 0, 0, 0);
            sacc[1][ni] = __builtin_amdgcn_mfma_f32_16x16x32_bf16(kf0, qf[1][0], sacc[1][ni], 0, 0, 0);
            sacc[0][ni] = __builtin_amdgcn_mfma_f32_16x16x32_bf16(kf1, qf[0][1], sacc[0][ni], 0, 0, 0);
            sacc[1][ni] = __builtin_amdgcn_mfma_f32_16x16x32_bf16(kf1, qf[1][1], sacc[1][ni], 0, 0, 0);
        }
        __builtin_amdgcn_s_setprio(0);
        const bool last = (t == nt - 1);

#pragma unroll
        for (int mi = 0; mi < 2; ++mi) {
            const int q = q0 + mi * 16 + l15;
            if (last) {
#pragma unroll
                for (int ni = 0; ni < 8; ++ni)
#pragma unroll
                    for (int jj = 0; jj < 4; ++jj)
                        if (t0 + ni * 16 + lg * 4 + jj > q) sacc[mi][ni][jj] = -1e9f;
            }
            float m = sacc[mi][0][0];
#pragma unroll
            for (int ni = 0; ni < 8; ++ni)
#pragma unroll
                for (int jj = 0; jj < 4; ++jj) m = fmaxf(m, sacc[mi][ni][jj]);
            m = fmaxf(m, __shfl_xor(m, 16, 64));
            m = fmaxf(m, __shfl_xor(m, 32, 64));
            float mnew = fmaxf(mrun[mi], m);
            float alpha = exp2f(mrun[mi] - mnew);
            float rs = 0.f;
#pragma unroll
            for (int ni = 0; ni < 8; ++ni)
#pragma unroll
                for (int jj = 0; jj < 4; ++jj) {
                    float pp = exp2f(sacc[mi][ni][jj] - mnew);
                    sacc[mi][ni][jj] = pp;
                    rs += pp;
                }
            rs += __shfl_xor(rs, 16, 64);
            rs += __shfl_xor(rs, 32, 64);
            lrun[mi] = lrun[mi] * alpha + rs;
            mrun[mi] = mnew;

            const int qh = mi * 16 + l15;
            const int pswz = (qh & 7) << 4;
#pragma unroll
            for (int ni = 0; ni < 8; ++ni) {
                u32 w0 = (u32)f2bf(sacc[mi][ni][0]) | ((u32)f2bf(sacc[mi][ni][1]) << 16);
                u32 w1 = (u32)f2bf(sacc[mi][ni][2]) | ((u32)f2bf(sacc[mi][ni][3]) << 16);
                uint2 w; w.x = w0; w.y = w1;
                *(uint2*)((char*)myP + qh * 256 + ((ni * 32 + lg * 8) ^ pswz)) = w;
            }
#pragma unroll
            for (int jj = 0; jj < 4; ++jj) {
                float aB = __shfl(alpha, (lane & 48) + ((lane >> 4) & 3) * 4 + jj, 64);
#pragma unroll
                for (int nd = 0; nd < 4; ++nd) oacc[mi][nd][jj] *= aB;
            }
        }

        __builtin_amdgcn_s_setprio(1);
#pragma unroll
        for (int ks = 0; ks < 4; ++ks) {
            bf16x8 pf[2];
#pragma unroll
            for (int mi = 0; mi < 2; ++mi) {
                const int qh = mi * 16 + l15;
                pf[mi] = *(const bf16x8*)((const char*)myP + qh * 256
                                          + ((ks * 64 + lg * 16) ^ ((qh & 7) << 4)));
            }
#pragma unroll
            for (int nd = 0; nd < 4; ++nd) {
                const int rr = nd * 16 + l15;
                bf16x8 vf = *(const bf16x8*)((const char*)lsV[cb] + rr * 256
                                             + ((ks * 64 + lg * 16) ^ ((rr & 15) << 4)));
                oacc[0][nd] = __builtin_amdgcn_mfma_f32_16x16x32_bf16(pf[0], vf, oacc[0][nd], 0, 0, 0);
                oacc[1][nd] = __builtin_amdgcn_mfma_f32_16x16x32_bf16(pf[1], vf, oacc[1][nd], 0, 0, 0);
            }
        }
        __builtin_amdgcn_s_setprio(0);

        if (t + 1 < nt) {
            const int nb = cb ^ 1;
            const int kswz = (kr & 7) << 4;
            *(uint4*)((char*)lsK[nb] + kr * 128 + ((kc * 16) ^ kswz)) = kg0;
            *(uint4*)((char*)lsK[nb] + (kr + 64) * 128 + ((kc * 16) ^ kswz)) = kg1;
            *(uint4*)((char*)lsV[nb] + vd * 256 + ((vc * 16) ^ ((vd & 15) << 4))) = vg0;
            *(uint4*)((char*)lsV[nb] + (vd + 32) * 256 + ((vc * 16) ^ (((vd + 32) & 15) << 4))) = vg1;
        }
    }

    if (hval) {
#pragma unroll
        for (int mi = 0; mi < 2; ++mi)
#pragma unroll
            for (int jj = 0; jj < 4; ++jj) {
                float lB = __shfl(lrun[mi], (lane & 48) + ((lane >> 4) & 3) * 4 + jj, 64);
                float inv = 1.0f / lB;
                int q = q0 + mi * 16 + lg * 4 + jj;
#pragma unroll
                for (int nd = 0; nd < 4; ++nd)
                    ctx[(size_t)q * KP + h * 64 + nd * 16 + l15] = f2bf(oacc[mi][nd][jj] * inv);
            }
    } else {
#pragma unroll
        for (int mi = 0; mi < 2; ++mi)
#pragma unroll
            for (int jj = 0; jj < 4; ++jj) {
                int q = q0 + mi * 16 + lg * 4 + jj;
#pragma unroll
                for (int nd = 0; nd < 4; ++nd)
                    ctx[(size_t)q * KP + HID + nd * 16 + l15] = 0;
            }
    }
}

extern "C" void kernel_launch(void* const* d_in, const int* in_sizes, int n_in,
                              void* d_out, int out_size, void* d_ws, size_t ws_size,
                              hipStream_t stream) {
    const float* hs      = (const float*)d_in[0];
    const float* w_qkv   = (const float*)d_in[2];
    const float* w_dense = (const float*)d_in[3];
    const float* cosb    = (const float*)d_in[4];
    const float* sinb    = (const float*)d_in[5];
    float* out = (float*)d_out;

    char* ws = (char*)d_ws;
    u16*   x_bf  = (u16*)(ws + 0);            // [2048][4608] bf16; reused as ctx
    u16*   wT    = (u16*)(ws + 18874368);     // [4864][4608] bf16 (wqkvT, later wdenT)
    char*  qP0   = ws + 63700992;             // QKV partials bf16 [2048][4672] x3
    char*  qP1   = ws + 82837504;
    char*  qP2   = ws + 101974016;
    u16*   q_bf  = (u16*)(ws + 121110528);    // [71][2048][64] bf16 (scaled)
    u16*   k_bf  = (u16*)(ws + 139722752);    // [2048][64]
    u16*   vT_bf = (u16*)(ws + 139984896);    // [64][2048]
    char*  dP1   = ws + 63700992;             // dense partials f32 [2048][4544] x2
    char*  dP2   = ws + 100925440;

    k_convert<<<2048, 256, 0, stream>>>(hs, x_bf);
    k_transpose<<<dim3(152, 144), 256, 0, stream>>>(w_qkv, wT, HID, NQKV, KP);
    k_gemm_sk<true><<<dim3(456), 512, 0, stream>>>(x_bf, wT, qP0, qP1, qP2, NQKV, 19);
    k_rope<<<SEQ, 256, 0, stream>>>((const u16*)qP0, (const u16*)qP1, (const u16*)qP2,
                                    cosb, sinb, q_bf, k_bf, vT_bf);
    k_attn<<<dim3(576), 512, 0, stream>>>(q_bf, k_bf, vT_bf, x_bf /*ctx*/);
    k_transpose<<<dim3(144, 144), 256, 0, stream>>>(w_dense, wT, HID, HID, KP);
    k_gemm_sk<false><<<dim3(432), 512, 0, stream>>>(x_bf /*ctx*/, wT,
                                                    (char*)out, dP1, dP2, HID, 18);
    k_reduce<<<2048, 256, 0, stream>>>(out, (const float*)dP1, (const float*)dP2,
                                       SEQ * HID / 4);
}

// Round 9
// 406.252 us; speedup vs baseline: 1.0636x; 1.0636x over previous
//
#include <hip/hip_runtime.h>

typedef unsigned short u16;
typedef unsigned int u32;
typedef __attribute__((ext_vector_type(8))) __bf16 bf16x8;
typedef __attribute__((ext_vector_type(4))) float f32x4;

#define SEQ   2048
#define NH    71
#define HD    64
#define HID   4544   // 71*64
#define NQKV  4672   // 73*64
#define KP    4608   // K padded to 72*64
#define KSL   1536   // split-K slice (KP/3); 48 K-tiles of 32

__device__ __forceinline__ u16 f2bf(float f) {
    __bf16 b = (__bf16)f;
    return __builtin_bit_cast(u16, b);
}
__device__ __forceinline__ float bf2f(u16 u) {
    __bf16 b = __builtin_bit_cast(__bf16, u);
    return (float)b;
}

__device__ __forceinline__ void gload_lds16(const u16* g, u16* l) {
    __builtin_amdgcn_global_load_lds(
        (const __attribute__((address_space(1))) u32*)g,
        (__attribute__((address_space(3))) u32*)l, 16, 0, 0);
}

// ---------------- f32 -> bf16, K-padded rows (zero pad) ----------------
__global__ __launch_bounds__(256) void k_convert(const float* __restrict__ in,
                                                 u16* __restrict__ out) {
    const int row = blockIdx.x;
    const float* src = in + (size_t)row * HID;
    u16* dst = out + (size_t)row * KP;
    for (int c = threadIdx.x; c < KP / 8; c += 256) {
        u16 o[8];
        if (c < HID / 8) {
            float4 v0 = *(const float4*)(src + c * 8);
            float4 v1 = *(const float4*)(src + c * 8 + 4);
            o[0] = f2bf(v0.x); o[1] = f2bf(v0.y); o[2] = f2bf(v0.z); o[3] = f2bf(v0.w);
            o[4] = f2bf(v1.x); o[5] = f2bf(v1.y); o[6] = f2bf(v1.z); o[7] = f2bf(v1.w);
        } else {
#pragma unroll
            for (int j = 0; j < 8; ++j) o[j] = 0;
        }
        *(uint4*)(dst + c * 8) = *(uint4*)o;
    }
}

// ----- transpose+convert: in[R][C] f32 -> out[Cp][Rp] bf16, zero-padded -----
// (rounds 4-7 verified version; 32x32 f32 tiles, guarded reads, zero K-pad)
__global__ __launch_bounds__(256) void k_transpose(const float* __restrict__ in,
                                                   u16* __restrict__ out,
                                                   int R, int C, int Rp) {
    __shared__ float tile[32][33];
    int c0 = blockIdx.x * 32, r0 = blockIdx.y * 32;
    int tx = threadIdx.x & 31, ty = threadIdx.x >> 5;
#pragma unroll
    for (int i = 0; i < 32; i += 8) {
        int r = r0 + ty + i, c = c0 + tx;
        tile[ty + i][tx] = (r < R && c < C) ? in[(size_t)r * C + c] : 0.f;
    }
    __syncthreads();
#pragma unroll
    for (int i = 0; i < 32; i += 8)
        out[(size_t)(c0 + ty + i) * Rp + r0 + tx] = f2bf(tile[tx][ty + i]);
}

// ---- split-K GEMM, 256x256 tile, BK=32, 4 LDS buffers, 3-deep prefetch ----
// (round-6 verified core: 16x16x32 MFMA, 0 bank conflicts, counted vmcnt(8))
// bf16 partial outputs for both GEMMs.
__global__ __launch_bounds__(512) void k_gemm_sk(const u16* __restrict__ A,
                                                 const u16* __restrict__ BT,
                                                 u16* __restrict__ C0,
                                                 u16* __restrict__ C1,
                                                 u16* __restrict__ C2,
                                                 int N, int ntN) {
    __shared__ u16 ls[4][256 * 64];            // 4 bufs x 32KB, packed A||B rows
    const int tid = threadIdx.x;
    const int lane = tid & 63;
    const int wid = tid >> 6;
    const int wr = wid >> 2, wc = wid & 3;     // 2 x 4 wave grid (128 x 64 out)
    const int l15 = lane & 15, lg = lane >> 4;

    const int p = blockIdx.x;
    const int m0 = (p & 7) * 256;              // XCD-chunk: XCD owns one m-strip
    const int rr_ = p >> 3;
    const int ks = rr_ / ntN;
    const int n0 = (rr_ % ntN) * 256;
    const int k0 = ks * KSL;

    const int sg = lane >> 3;
    const int slot = lane & 7;
    const u16* sb[4];
    int dstoff[4];
#pragma unroll
    for (int i = 0; i < 4; ++i) {
        int r = i * 64 + wid * 8 + sg;
        int sc = slot ^ (r & 7);
        sb[i] = (sc < 4) ? (A  + (size_t)(m0 + r) * KP + k0 + sc * 8)
                         : (BT + (size_t)(n0 + r) * KP + k0 + (sc ^ 4) * 8);
        dstoff[i] = r * 64 + slot * 8;
    }

    f32x4 acc[8][4];
#pragma unroll
    for (int i = 0; i < 8; ++i)
#pragma unroll
        for (int j = 0; j < 4; ++j) acc[i][j] = (f32x4){0.f, 0.f, 0.f, 0.f};

#define STG(d, kt, i) gload_lds16(sb[i] + (size_t)(kt) * 32, &ls[d][dstoff[i]])

    const int NT = KSL / 32;  // 48
    STG(0, 0, 0); STG(0, 0, 1); STG(0, 0, 2); STG(0, 0, 3);
    STG(1, 1, 0); STG(1, 1, 1); STG(1, 1, 2); STG(1, 1, 3);
    STG(2, 2, 0); STG(2, 2, 1); STG(2, 2, 2); STG(2, 2, 3);
    asm volatile("s_waitcnt vmcnt(8)" ::: "memory");
    __builtin_amdgcn_s_barrier();

    for (int kt = 0; kt < NT; ++kt) {
        const u16* L = ls[kt & 3];
        const int db = (kt + 3) & 3;
        const bool st = (kt + 3 < NT);
        bf16x8 bfr[4], af[4];
        // ---- phase 1: ds_read B(all ni) + A(mi0-3); stage 2; MFMA mi0-3
#pragma unroll
        for (int ni = 0; ni < 4; ++ni) {
            int rb = wc * 64 + ni * 16 + l15;
            bfr[ni] = *(const bf16x8*)(L + rb * 64 + ((lg ^ (rb & 7) ^ 4) << 3));
        }
#pragma unroll
        for (int mi = 0; mi < 4; ++mi) {
            int ra = wr * 128 + mi * 16 + l15;
            af[mi] = *(const bf16x8*)(L + ra * 64 + ((lg ^ (ra & 7)) << 3));
        }
        if (st) { STG(db, kt + 3, 0); STG(db, kt + 3, 1); }
        __builtin_amdgcn_s_barrier();
        __builtin_amdgcn_s_setprio(1);
#pragma unroll
        for (int mi = 0; mi < 4; ++mi)
#pragma unroll
            for (int ni = 0; ni < 4; ++ni)
                acc[mi][ni] = __builtin_amdgcn_mfma_f32_16x16x32_bf16(
                    af[mi], bfr[ni], acc[mi][ni], 0, 0, 0);
        __builtin_amdgcn_s_setprio(0);
        __builtin_amdgcn_s_barrier();
        // ---- phase 2: ds_read A(mi4-7); stage 2; MFMA mi4-7
#pragma unroll
        for (int mi = 0; mi < 4; ++mi) {
            int ra = wr * 128 + (mi + 4) * 16 + l15;
            af[mi] = *(const bf16x8*)(L + ra * 64 + ((lg ^ (ra & 7)) << 3));
        }
        if (st) { STG(db, kt + 3, 2); STG(db, kt + 3, 3); }
        __builtin_amdgcn_s_barrier();
        __builtin_amdgcn_s_setprio(1);
#pragma unroll
        for (int mi = 0; mi < 4; ++mi)
#pragma unroll
            for (int ni = 0; ni < 4; ++ni)
                acc[mi + 4][ni] = __builtin_amdgcn_mfma_f32_16x16x32_bf16(
                    af[mi], bfr[ni], acc[mi + 4][ni], 0, 0, 0);
        __builtin_amdgcn_s_setprio(0);
        if (kt < NT - 3)       asm volatile("s_waitcnt vmcnt(8)" ::: "memory");
        else if (kt == NT - 3) asm volatile("s_waitcnt vmcnt(4)" ::: "memory");
        else if (kt == NT - 2) asm volatile("s_waitcnt vmcnt(0)" ::: "memory");
        __builtin_amdgcn_s_barrier();
    }
#undef STG

    u16* Cks = (ks == 0) ? C0 : (ks == 1) ? C1 : C2;
#pragma unroll
    for (int mi = 0; mi < 8; ++mi)
#pragma unroll
        for (int ni = 0; ni < 4; ++ni) {
            int row = m0 + wr * 128 + mi * 16 + lg * 4;
            int col = n0 + wc * 64 + ni * 16 + l15;
            if (col < N) {
#pragma unroll
                for (int j = 0; j < 4; ++j)
                    Cks[(size_t)(row + j) * N + col] = f2bf(acc[mi][ni][j]);
            }
        }
}

// -------- dense split-K reduction: out = P0 + P1 + P2 (bf16 in, f32 out) --------
__global__ __launch_bounds__(256) void k_reduce(const u16* __restrict__ P0,
                                                const u16* __restrict__ P1,
                                                const u16* __restrict__ P2,
                                                float* __restrict__ out, int n8) {
    for (int i = blockIdx.x * 256 + threadIdx.x; i < n8; i += gridDim.x * 256) {
        uint4 a = ((const uint4*)P0)[i];
        uint4 b = ((const uint4*)P1)[i];
        uint4 c = ((const uint4*)P2)[i];
        float r[8];
#pragma unroll
        for (int j = 0; j < 4; ++j) {
            u32 aw = (&a.x)[j], bw = (&b.x)[j], cw = (&c.x)[j];
            r[j * 2]     = bf2f((u16)(aw & 0xffff)) + bf2f((u16)(bw & 0xffff))
                         + bf2f((u16)(cw & 0xffff));
            r[j * 2 + 1] = bf2f((u16)(aw >> 16)) + bf2f((u16)(bw >> 16))
                         + bf2f((u16)(cw >> 16));
        }
        ((float4*)out)[i * 2]     = (float4){r[0], r[1], r[2], r[3]};
        ((float4*)out)[i * 2 + 1] = (float4){r[4], r[5], r[6], r[7]};
    }
}

// ---------------- RoPE + split-K sum + split/transposed emit ----------------
__global__ __launch_bounds__(256) void k_rope(const u16* __restrict__ P0,
                                              const u16* __restrict__ P1,
                                              const u16* __restrict__ P2,
                                              const float* __restrict__ cosb,
                                              const float* __restrict__ sinb,
                                              u16* __restrict__ qb, u16* __restrict__ kb,
                                              u16* __restrict__ vT) {
    int s = blockIdx.x;
    __shared__ float row[NQKV];
    __shared__ float cs[64], sn[64];
    if (threadIdx.x < 64) {
        cs[threadIdx.x] = cosb[s * 64 + threadIdx.x];
        sn[threadIdx.x] = sinb[s * 64 + threadIdx.x];
    }
    const u16* r0 = P0 + (size_t)s * NQKV;
    const u16* r1 = P1 + (size_t)s * NQKV;
    const u16* r2 = P2 + (size_t)s * NQKV;
    for (int e = threadIdx.x; e < NQKV; e += 256)
        row[e] = bf2f(r0[e]) + bf2f(r1[e]) + bf2f(r2[e]);
    __syncthreads();
    const float qscale = 0.125f * 1.44269504f;
    for (int e = threadIdx.x; e < NQKV; e += 256) {
        int h = e >> 6, d = e & 63;
        float x = row[e];
        if (h < 72) {
            float other = row[h * 64 + ((d < 32) ? d + 32 : d - 32)];
            float rot = (d < 32) ? -other : other;
            float rr = x * cs[d] + rot * sn[d];
            if (h < NH) qb[((size_t)h * SEQ + s) * 64 + d] = f2bf(rr * qscale);
            else        kb[(size_t)s * 64 + d] = f2bf(rr);
        } else {
            vT[(size_t)d * SEQ + s] = f2bf(x);
        }
    }
}

// ---------------- Flash attention (round-6 structure + setprio + defer-max) ----------------
__global__ __launch_bounds__(512) void k_attn(const u16* __restrict__ qb,
                                              const u16* __restrict__ kb,
                                              const u16* __restrict__ vT,
                                              u16* __restrict__ ctx) {
    const int tid = threadIdx.x;
    const int lane = tid & 63;
    const int wid = tid >> 6;
    const int l15 = lane & 15, lg = lane >> 4;

    const int bid = blockIdx.x;
    const int qt = 63 - bid / 9;
    const int hg = bid % 9;
    int h = hg * 8 + wid;
    const bool hval = (h < NH);
    if (!hval) h = NH - 1;
    const int q0 = qt * 32;
    const int nt = (qt >> 2) + 1;

    __shared__ u16 lsK[2][128 * 64];
    __shared__ u16 lsV[2][64 * 128];
    __shared__ u16 lsP[8][32 * 128];
    u16* myP = lsP[wid];

    const int kr = tid >> 3, kc = tid & 7;
    const int vd = tid >> 4, vc = tid & 15;

    bf16x8 qf[2][2];
#pragma unroll
    for (int mi = 0; mi < 2; ++mi)
#pragma unroll
        for (int ks = 0; ks < 2; ++ks)
            qf[mi][ks] = *(const bf16x8*)(qb + ((size_t)h * SEQ + q0 + mi * 16 + l15) * 64
                                          + ks * 32 + lg * 8);

    f32x4 oacc[2][4];
#pragma unroll
    for (int i = 0; i < 2; ++i)
#pragma unroll
        for (int j = 0; j < 4; ++j) oacc[i][j] = (f32x4){0.f, 0.f, 0.f, 0.f};
    float mrun[2] = {-3e38f, -3e38f};
    float lrun[2] = {0.f, 0.f};

    uint4 kg0, kg1, vg0, vg1;
    kg0 = *(const uint4*)(kb + (size_t)kr * 64 + kc * 8);
    kg1 = *(const uint4*)(kb + (size_t)(kr + 64) * 64 + kc * 8);
    vg0 = *(const uint4*)(vT + (size_t)vd * SEQ + vc * 8);
    vg1 = *(const uint4*)(vT + (size_t)(vd + 32) * SEQ + vc * 8);
    {
        const int kswz = (kr & 7) << 4;
        *(uint4*)((char*)lsK[0] + kr * 128 + ((kc * 16) ^ kswz)) = kg0;
        *(uint4*)((char*)lsK[0] + (kr + 64) * 128 + ((kc * 16) ^ kswz)) = kg1;
        *(uint4*)((char*)lsV[0] + vd * 256 + ((vc * 16) ^ ((vd & 15) << 4))) = vg0;
        *(uint4*)((char*)lsV[0] + (vd + 32) * 256 + ((vc * 16) ^ (((vd + 32) & 15) << 4))) = vg1;
    }

    for (int t = 0; t < nt; ++t) {
        const int t0 = t << 7;
        const int cb = t & 1;
        if (t + 1 < nt) {
            const int t1 = t0 + 128;
            kg0 = *(const uint4*)(kb + (size_t)(t1 + kr) * 64 + kc * 8);
            kg1 = *(const uint4*)(kb + (size_t)(t1 + kr + 64) * 64 + kc * 8);
            vg0 = *(const uint4*)(vT + (size_t)vd * SEQ + t1 + vc * 8);
            vg1 = *(const uint4*)(vT + (size_t)(vd + 32) * SEQ + t1 + vc * 8);
        }
        __syncthreads();

        f32x4 sacc[2][8];
#pragma unroll
        for (int i = 0; i < 2; ++i)
#pragma unroll
            for (int j = 0; j < 8; ++j) sacc[i][j] = (f32x4){0.f, 0.f, 0.f, 0.f};
        __builtin_amdgcn_s_setprio(1);
#pragma unroll
        for (int ni = 0; ni < 8; ++ni) {
            const int rr = ni * 16 + l15;
            const int swz = (rr & 7) << 4;
            bf16x8 kf0 = *(const bf16x8*)((const char*)lsK[cb] + rr * 128 + ((lg * 16) ^ swz));
            bf16x8 kf1 = *(const bf16x8*)((const char*)lsK[cb] + rr * 128 + ((64 + lg * 16) ^ swz));
            sacc[0][ni] = __builtin_amdgcn_mfma_f32_16x16x32_bf16(kf0, qf[0][0], sacc[0][ni], 0, 0, 0);
            sacc[1][ni] = __builtin_amdgcn_mfma_f32_16x16x32_bf16(kf0, qf[1][0], sacc[1][ni], 0, 0, 0);
            sacc[0][ni] = __builtin_amdgcn_mfma_f32_16x16x32_bf16(kf1, qf[0][1], sacc[0][ni], 0, 0, 0);
            sacc[1][ni] = __builtin_amdgcn_mfma_f32_16x16x32_bf16(kf1, qf[1][1], sacc[1][ni], 0, 0, 0);
        }
        __builtin_amdgcn_s_setprio(0);
        const bool last = (t == nt - 1);

#pragma unroll
        for (int mi = 0; mi < 2; ++mi) {
            const int q = q0 + mi * 16 + l15;
            if (last) {
#pragma unroll
                for (int ni = 0; ni < 8; ++ni)
#pragma unroll
                    for (int jj = 0; jj < 4; ++jj)
                        if (t0 + ni * 16 + lg * 4 + jj > q) sacc[mi][ni][jj] = -1e9f;
            }
            float m = sacc[mi][0][0];
#pragma unroll
            for (int ni = 0; ni < 8; ++ni)
#pragma unroll
                for (int jj = 0; jj < 4; ++jj) m = fmaxf(m, sacc[mi][ni][jj]);
            m = fmaxf(m, __shfl_xor(m, 16, 64));
            m = fmaxf(m, __shfl_xor(m, 32, 64));
            // T13 defer-max: skip rescale when the max didn't grow by > 8
            float mnew = fmaxf(mrun[mi], m);
            const bool skiprs = (__all(mnew - mrun[mi] <= 8.0f) != 0);
            float mref = skiprs ? mrun[mi] : mnew;
            float rs = 0.f;
#pragma unroll
            for (int ni = 0; ni < 8; ++ni)
#pragma unroll
                for (int jj = 0; jj < 4; ++jj) {
                    float pp = exp2f(sacc[mi][ni][jj] - mref);
                    sacc[mi][ni][jj] = pp;
                    rs += pp;
                }
            rs += __shfl_xor(rs, 16, 64);
            rs += __shfl_xor(rs, 32, 64);
            if (skiprs) {
                lrun[mi] += rs;
            } else {
                float alpha = exp2f(mrun[mi] - mnew);
                lrun[mi] = lrun[mi] * alpha + rs;
                mrun[mi] = mnew;
#pragma unroll
                for (int jj = 0; jj < 4; ++jj) {
                    float aB = __shfl(alpha, (lane & 48) + ((lane >> 4) & 3) * 4 + jj, 64);
#pragma unroll
                    for (int nd = 0; nd < 4; ++nd) oacc[mi][nd][jj] *= aB;
                }
            }

            const int qh = mi * 16 + l15;
            const int pswz = (qh & 7) << 4;
#pragma unroll
            for (int ni = 0; ni < 8; ++ni) {
                u32 w0 = (u32)f2bf(sacc[mi][ni][0]) | ((u32)f2bf(sacc[mi][ni][1]) << 16);
                u32 w1 = (u32)f2bf(sacc[mi][ni][2]) | ((u32)f2bf(sacc[mi][ni][3]) << 16);
                uint2 w; w.x = w0; w.y = w1;
                *(uint2*)((char*)myP + qh * 256 + ((ni * 32 + lg * 8) ^ pswz)) = w;
            }
        }

        __builtin_amdgcn_s_setprio(1);
#pragma unroll
        for (int ks = 0; ks < 4; ++ks) {
            bf16x8 pf[2];
#pragma unroll
            for (int mi = 0; mi < 2; ++mi) {
                const int qh = mi * 16 + l15;
                pf[mi] = *(const bf16x8*)((const char*)myP + qh * 256
                                          + ((ks * 64 + lg * 16) ^ ((qh & 7) << 4)));
            }
#pragma unroll
            for (int nd = 0; nd < 4; ++nd) {
                const int rr = nd * 16 + l15;
                bf16x8 vf = *(const bf16x8*)((const char*)lsV[cb] + rr * 256
                                             + ((ks * 64 + lg * 16) ^ ((rr & 15) << 4)));
                oacc[0][nd] = __builtin_amdgcn_mfma_f32_16x16x32_bf16(pf[0], vf, oacc[0][nd], 0, 0, 0);
                oacc[1][nd] = __builtin_amdgcn_mfma_f32_16x16x32_bf16(pf[1], vf, oacc[1][nd], 0, 0, 0);
            }
        }
        __builtin_amdgcn_s_setprio(0);

        if (t + 1 < nt) {
            const int nb = cb ^ 1;
            const int kswz = (kr & 7) << 4;
            *(uint4*)((char*)lsK[nb] + kr * 128 + ((kc * 16) ^ kswz)) = kg0;
            *(uint4*)((char*)lsK[nb] + (kr + 64) * 128 + ((kc * 16) ^ kswz)) = kg1;
            *(uint4*)((char*)lsV[nb] + vd * 256 + ((vc * 16) ^ ((vd & 15) << 4))) = vg0;
            *(uint4*)((char*)lsV[nb] + (vd + 32) * 256 + ((vc * 16) ^ (((vd + 32) & 15) << 4))) = vg1;
        }
    }

    if (hval) {
#pragma unroll
        for (int mi = 0; mi < 2; ++mi)
#pragma unroll
            for (int jj = 0; jj < 4; ++jj) {
                float lB = __shfl(lrun[mi], (lane & 48) + ((lane >> 4) & 3) * 4 + jj, 64);
                float inv = 1.0f / lB;
                int q = q0 + mi * 16 + lg * 4 + jj;
#pragma unroll
                for (int nd = 0; nd < 4; ++nd)
                    ctx[(size_t)q * KP + h * 64 + nd * 16 + l15] = f2bf(oacc[mi][nd][jj] * inv);
            }
    } else {
#pragma unroll
        for (int mi = 0; mi < 2; ++mi)
#pragma unroll
            for (int jj = 0; jj < 4; ++jj) {
                int q = q0 + mi * 16 + lg * 4 + jj;
#pragma unroll
                for (int nd = 0; nd < 4; ++nd)
                    ctx[(size_t)q * KP + HID + nd * 16 + l15] = 0;
            }
    }
}

extern "C" void kernel_launch(void* const* d_in, const int* in_sizes, int n_in,
                              void* d_out, int out_size, void* d_ws, size_t ws_size,
                              hipStream_t stream) {
    const float* hs      = (const float*)d_in[0];
    const float* w_qkv   = (const float*)d_in[2];
    const float* w_dense = (const float*)d_in[3];
    const float* cosb    = (const float*)d_in[4];
    const float* sinb    = (const float*)d_in[5];
    float* out = (float*)d_out;

    char* ws = (char*)d_ws;
    u16*   x_bf  = (u16*)(ws + 0);            // [2048][4608] bf16; reused as ctx
    u16*   wT    = (u16*)(ws + 18874368);     // [4864][4608] bf16 (wqkvT, later wdenT)
    u16*   qP0   = (u16*)(ws + 63700992);     // QKV partials bf16 [2048][4672] x3
    u16*   qP1   = (u16*)(ws + 82837504);
    u16*   qP2   = (u16*)(ws + 101974016);
    u16*   q_bf  = (u16*)(ws + 121110528);    // [71][2048][64] bf16 (scaled)
    u16*   k_bf  = (u16*)(ws + 139722752);    // [2048][64]
    u16*   vT_bf = (u16*)(ws + 139984896);    // [64][2048]
    u16*   dP0   = (u16*)(ws + 63700992);     // dense partials bf16 [2048][4544] x3
    u16*   dP1   = (u16*)(ws + 82837504);     //   (overlap qP*, dead after rope)
    u16*   dP2   = (u16*)(ws + 101974016);

    k_convert<<<2048, 256, 0, stream>>>(hs, x_bf);
    k_transpose<<<dim3(152, 144), 256, 0, stream>>>(w_qkv, wT, HID, NQKV, KP);
    k_gemm_sk<<<dim3(456), 512, 0, stream>>>(x_bf, wT, qP0, qP1, qP2, NQKV, 19);
    k_rope<<<SEQ, 256, 0, stream>>>(qP0, qP1, qP2, cosb, sinb, q_bf, k_bf, vT_bf);
    k_attn<<<dim3(576), 512, 0, stream>>>(q_bf, k_bf, vT_bf, x_bf /*ctx*/);
    k_transpose<<<dim3(144, 144), 256, 0, stream>>>(w_dense, wT, HID, HID, KP);
    k_gemm_sk<<<dim3(432), 512, 0, stream>>>(x_bf /*ctx*/, wT, dP0, dP1, dP2, HID, 18);
    k_reduce<<<2048, 256, 0, stream>>>(dP0, dP1, dP2, out, SEQ * HID / 8);
}